// Round 1
// 219.103 us; speedup vs baseline: 1.0269x; 1.0269x over previous
//
#include <hip/hip_runtime.h>
#include <hip/hip_bf16.h>

#define NN 50000
#define NE 800000
#define DIM 128
#define CAP 64          // padded-CSR slots per destination row (mean degree 16)

typedef __attribute__((ext_vector_type(8))) short short8_t;           // 8 bf16 for MFMA
typedef __attribute__((ext_vector_type(8))) unsigned short ushort8_t; // 8 bf16 raw
typedef __attribute__((ext_vector_type(4))) float floatx4;

static __device__ inline unsigned short f2bf(float x){        // RNE float->bf16
  unsigned int u = __float_as_uint(x);
  unsigned int r = (u + 0x7FFF + ((u >> 16) & 1)) >> 16;
  return (unsigned short)r;
}
static __device__ inline float bf2f(unsigned short u){
  return __uint_as_float(((unsigned int)u) << 16);
}

// K0: heterogeneous setup. Block 0: fold W into attention vectors
// (v1 = a1^T W, v2 = a2^T W, c1 = b.a1 + a_bias, c2 = b.a2).
// Blocks 1..32: T f32 -> bf16. Blocks 33..228: zero count.
__global__ __launch_bounds__(256) void k_setup(const float* __restrict__ W,
                       const float* __restrict__ wb,
                       const float* __restrict__ aw, const float* __restrict__ ab,
                       float* __restrict__ v12c,
                       const float4* __restrict__ T4, ushort4* __restrict__ Tb4,
                       int* __restrict__ count){
  int b = blockIdx.x;
  int t = threadIdx.x;
  if (b == 0){
    __shared__ float r1[DIM], r2[DIM];
    if (t < DIM){
      float s1 = 0.f, s2 = 0.f;
      for (int j = 0; j < DIM; ++j){
        float w = W[j*DIM + t];
        s1 += aw[j] * w;
        s2 += aw[DIM + j] * w;
      }
      v12c[t] = s1;
      v12c[DIM + t] = s2;
      float bb = wb[t];
      r1[t] = bb * aw[t];
      r2[t] = bb * aw[DIM + t];
    }
    __syncthreads();
    if (t == 0){
      float a1s = 0.f, a2s = 0.f;
      for (int j = 0; j < DIM; ++j){ a1s += r1[j]; a2s += r2[j]; }
      v12c[2*DIM]   = a1s + ab[0];
      v12c[2*DIM+1] = a2s;
    }
  } else if (b <= 32){
    int i = (b-1)*256 + t;              // 8192 float4s of T
    float4 v = T4[i];
    Tb4[i] = make_ushort4(f2bf(v.x), f2bf(v.y), f2bf(v.z), f2bf(v.w));
  } else {
    int i = (b-33)*256 + t;
    if (i < NN) count[i] = 0;
  }
}

// K1: p1/p2 per node + bf16 emb copy + fused histogram whose atomicAdd
// RETURN VALUE is the edge's slot in a PADDED CSR row -> scatter happens
// right here. Kills rank[], both scans, and the separate scatter kernel.
__global__ __launch_bounds__(256) void k_pvec(const float4* __restrict__ emb4,
                      const float* __restrict__ v12c,
                      float* __restrict__ p1, float* __restrict__ p2,
                      unsigned short* __restrict__ embh,
                      const int* __restrict__ dst, const int* __restrict__ srcp,
                      int* __restrict__ count, int* __restrict__ csr){
  int tid = blockIdx.x * 256 + threadIdx.x;
  if (tid < NE){
    int d = dst[tid];
    int s = srcp[tid];
    int r = atomicAdd(&count[d], 1);
    if (r < CAP) csr[(d << 6) + r] = s;   // overflow (P~1e-13) dropped, no corruption
  }
  int g = threadIdx.x & 31;
  int i = blockIdx.x * 8 + (threadIdx.x >> 5);
  if (i >= NN) return;
  float4 e = emb4[i*32 + g];
  *(ushort4*)(embh + i*DIM + g*4) =
      make_ushort4(f2bf(e.x), f2bf(e.y), f2bf(e.z), f2bf(e.w));
  float4 a = ((const float4*)v12c)[g];
  float4 b = ((const float4*)v12c)[32 + g];
  float s1 = e.x*a.x + e.y*a.y + e.z*a.z + e.w*a.w;
  float s2 = e.x*b.x + e.y*b.y + e.z*b.z + e.w*b.w;
  #pragma unroll
  for (int off = 16; off; off >>= 1){
    s1 += __shfl_down(s1, off, 32);
    s2 += __shfl_down(s2, off, 32);
  }
  if (g == 0){
    p1[i] = s1 + v12c[256];
    p2[i] = s2 + v12c[257];
  }
}

// K2: one 64-lane wave per destination node, 4 edges in flight
// (16 lanes x 16B = one 256B bf16 row each). Padded-CSR row: base = n<<6,
// valid slots = min(count[n], CAP). attn computed inline
// (p2[s] is an L2-resident broadcast read). fp32 accum, bf16 row store.
__global__ __launch_bounds__(256) void k_gather(const int* __restrict__ count,
                       const int* __restrict__ csr,
                       const float* __restrict__ p1, const float* __restrict__ p2,
                       const unsigned short* __restrict__ embh,
                       unsigned short* __restrict__ aggh){
  int lane = threadIdx.x & 63;
  int c16 = lane & 15;                 // column slot (8 bf16 each)
  int g4 = lane >> 4;                  // edge slot 0..3
  int n = blockIdx.x * 4 + (threadIdx.x >> 6);
  if (n >= NN) return;
  int cnt = count[n];
  cnt = cnt < CAP ? cnt : CAP;
  int s0 = n << 6;
  float p1n = p1[n];
  float acc[8] = {0.f,0.f,0.f,0.f,0.f,0.f,0.f,0.f};
  float dsum = 0.f;
  for (int e = g4; e < cnt; e += 4){
    int s = csr[s0 + e];                             // broadcast per 16-lane group
    float sc = p1n + p2[s];                          // L2-resident (200 KB)
    sc = sc > 0.f ? sc : 0.2f * sc;
    float a = __expf(sc);
    dsum += a;
    ushort8_t v = *(const ushort8_t*)(embh + s*DIM + c16*8);  // 256B/group
    #pragma unroll
    for (int j = 0; j < 8; ++j) acc[j] += a * bf2f(v[j]);
  }
  #pragma unroll
  for (int j = 0; j < 8; ++j){
    acc[j] += __shfl_xor(acc[j], 16, 64);
    acc[j] += __shfl_xor(acc[j], 32, 64);
  }
  dsum += __shfl_xor(dsum, 16, 64);
  dsum += __shfl_xor(dsum, 32, 64);
  if (g4 == 0){
    float dinv = 1.0f / (dsum + 1e-20f);
    ushort8_t o;
    #pragma unroll
    for (int j = 0; j < 8; ++j) o[j] = f2bf(acc[j] * dinv);
    *(ushort8_t*)(aggh + n*DIM + c16*8) = o;
  }
}

// K3: MFMA GEMM h = [embh|aggh] @ Tb^T + tb, fused LayerNorm.
// Block = 4 waves x 16 nodes; barrier-free, B frags L2-broadcast.
__global__ __launch_bounds__(256) void k_out(const unsigned short* __restrict__ embh,
                     const unsigned short* __restrict__ aggh,
                     const unsigned short* __restrict__ Tb,
                     const float* __restrict__ tb,
                     const float* __restrict__ gamma, const float* __restrict__ beta,
                     float* __restrict__ out){
  int t = threadIdx.x;
  int w = t >> 6;
  int lane = t & 63;
  int m16 = lane & 15;
  int q = lane >> 4;                         // 0..3
  int nodebase = blockIdx.x * 64 + w * 16;
  int nA = nodebase + m16;
  int nAc = (nA < NN) ? nA : 0;              // clamp loads; stores guarded
  floatx4 acc[8];
  #pragma unroll
  for (int ct = 0; ct < 8; ++ct) acc[ct] = (floatx4){0.f, 0.f, 0.f, 0.f};

  #pragma unroll
  for (int kc = 0; kc < 8; ++kc){
    int k0 = kc*32 + q*8;
    const unsigned short* aptr = (kc < 4) ? (embh + nAc*DIM + k0)
                                          : (aggh + nAc*DIM + (k0 - 128));
    short8_t afrag = *(const short8_t*)aptr;           // A[m=m16][k0..k0+7]
    #pragma unroll
    for (int ct = 0; ct < 8; ++ct){
      short8_t bfrag = *(const short8_t*)(Tb + (ct*16 + m16)*256 + k0); // B[k][j]=T[j][k]
      acc[ct] = __builtin_amdgcn_mfma_f32_16x16x32_bf16(afrag, bfrag, acc[ct], 0, 0, 0);
    }
  }

  float tbv[8], gmv[8], btv[8];
  #pragma unroll
  for (int ct = 0; ct < 8; ++ct){
    int col = ct*16 + m16;
    tbv[ct] = tb[col]; gmv[ct] = gamma[col]; btv[ct] = beta[col];
  }
  #pragma unroll
  for (int r = 0; r < 4; ++r){
    int n = nodebase + q*4 + r;              // D row = q*4 + reg
    float h[8]; float s = 0.f, ss = 0.f;
    #pragma unroll
    for (int ct = 0; ct < 8; ++ct){
      h[ct] = acc[ct][r] + tbv[ct];
      s += h[ct]; ss += h[ct]*h[ct];
    }
    #pragma unroll
    for (int off = 1; off < 16; off <<= 1){
      s  += __shfl_xor(s,  off, 16);
      ss += __shfl_xor(ss, off, 16);
    }
    float mu = s * (1.f/128.f);
    float var = ss * (1.f/128.f) - mu*mu;
    float rstd = rsqrtf(var + 1e-5f);
    if (n < NN){
      #pragma unroll
      for (int ct = 0; ct < 8; ++ct){
        out[n*DIM + ct*16 + m16] = (h[ct]-mu)*rstd*gmv[ct] + btv[ct];
      }
    }
  }
}

extern "C" void kernel_launch(void* const* d_in, const int* in_sizes, int n_in,
                              void* d_out, int out_size, void* d_ws, size_t ws_size,
                              hipStream_t stream){
  const float* emb          = (const float*)d_in[0];
  const int*   edges        = (const int*)d_in[1];
  const float* w_weight     = (const float*)d_in[2];
  const float* w_bias       = (const float*)d_in[3];
  const float* a_weight     = (const float*)d_in[4];
  const float* a_bias       = (const float*)d_in[5];
  const float* trans_weight = (const float*)d_in[6];
  const float* trans_bias   = (const float*)d_in[7];
  const float* ln_gamma     = (const float*)d_in[8];
  const float* ln_beta      = (const float*)d_in[9];
  float* out = (float*)d_out;

  // ws layout (float offsets), ws is 256 MiB (poison fills = 262144 KB):
  // p1[50k] p2[50k] v12c[320] | ints: count[50k] csr_pad[3.2M] |
  //   embh bf16[6.4M] | aggh bf16[6.4M] | Tb bf16[32768]
  float* ws      = (float*)d_ws;
  float* p1      = ws;
  float* p2      = ws + 50000;
  float* v12c    = ws + 100000;
  int*   count   = (int*)(ws + 100320);
  int*   csr     = (int*)(ws + 150320);
  unsigned short* embh = (unsigned short*)(ws + 3350320);
  unsigned short* aggh = (unsigned short*)(ws + 6550320);
  unsigned short* Tb   = (unsigned short*)(ws + 9750320);

  const int* e_dst = edges;
  const int* e_src = edges + NE;

  k_setup<<<229, 256, 0, stream>>>(w_weight, w_bias, a_weight, a_bias, v12c,
                                   (const float4*)trans_weight, (ushort4*)Tb, count);
  k_pvec<<<(NN + 7)/8, 256, 0, stream>>>((const float4*)emb, v12c, p1, p2,
                                         embh, e_dst, e_src, count, csr);
  k_gather<<<(NN + 3)/4, 256, 0, stream>>>(count, csr, p1, p2, embh, aggh);
  k_out<<<(NN + 63)/64, 256, 0, stream>>>(embh, aggh, Tb, trans_bias,
                                          ln_gamma, ln_beta, out);
}

// Round 2
// 206.505 us; speedup vs baseline: 1.0895x; 1.0610x over previous
//
#include <hip/hip_runtime.h>
#include <hip/hip_bf16.h>

#define NN 50000
#define NE 800000
#define DIM 128
#define SHARDS 4        // counter shards per node (shard = tid&3)
#define SCAP 32         // slots per shard (lambda=4 -> P(overflow) ~ 1e-20)
// padded CSR row = SHARDS*SCAP = 128 int slots; counter (n,s) padded to own 64B line

typedef __attribute__((ext_vector_type(8))) short short8_t;           // 8 bf16 for MFMA
typedef __attribute__((ext_vector_type(8))) unsigned short ushort8_t; // 8 bf16 raw
typedef __attribute__((ext_vector_type(4))) float floatx4;

static __device__ inline unsigned short f2bf(float x){        // RNE float->bf16
  unsigned int u = __float_as_uint(x);
  unsigned int r = (u + 0x7FFF + ((u >> 16) & 1)) >> 16;
  return (unsigned short)r;
}
static __device__ inline float bf2f(unsigned short u){
  return __uint_as_float(((unsigned int)u) << 16);
}

// K0: heterogeneous setup. Block 0: fold W into attention vectors
// (v1 = a1^T W, v2 = a2^T W, c1 = b.a1 + a_bias, c2 = b.a2).
// Blocks 1..32: T f32 -> bf16. Blocks 33..3157: zero padded counters (12.8MB).
__global__ __launch_bounds__(256) void k_setup(const float* __restrict__ W,
                       const float* __restrict__ wb,
                       const float* __restrict__ aw, const float* __restrict__ ab,
                       float* __restrict__ v12c,
                       const float4* __restrict__ T4, ushort4* __restrict__ Tb4,
                       int4* __restrict__ count4){
  int b = blockIdx.x;
  int t = threadIdx.x;
  if (b == 0){
    __shared__ float r1[DIM], r2[DIM];
    if (t < DIM){
      float s1 = 0.f, s2 = 0.f;
      for (int j = 0; j < DIM; ++j){
        float w = W[j*DIM + t];
        s1 += aw[j] * w;
        s2 += aw[DIM + j] * w;
      }
      v12c[t] = s1;
      v12c[DIM + t] = s2;
      float bb = wb[t];
      r1[t] = bb * aw[t];
      r2[t] = bb * aw[DIM + t];
    }
    __syncthreads();
    if (t == 0){
      float a1s = 0.f, a2s = 0.f;
      for (int j = 0; j < DIM; ++j){ a1s += r1[j]; a2s += r2[j]; }
      v12c[2*DIM]   = a1s + ab[0];
      v12c[2*DIM+1] = a2s;
    }
  } else if (b <= 32){
    int i = (b-1)*256 + t;              // 8192 float4s of T
    float4 v = T4[i];
    Tb4[i] = make_ushort4(f2bf(v.x), f2bf(v.y), f2bf(v.z), f2bf(v.w));
  } else {
    int i = (b-33)*256 + t;             // 800000 int4s = 3.2M ints
    count4[i] = make_int4(0,0,0,0);
  }
}

// K1: p1/p2 per node + bf16 emb copy + fused sharded histogram.
// Counter (d, tid&3) sits on its own 64B line -> per-line RMW serialization 4
// (was 256 on the dense array). atomic return IS the padded-CSR slot.
__global__ __launch_bounds__(256) void k_pvec(const float4* __restrict__ emb4,
                      const float* __restrict__ v12c,
                      float* __restrict__ p1, float* __restrict__ p2,
                      unsigned short* __restrict__ embh,
                      const int* __restrict__ dst, const int* __restrict__ srcp,
                      int* __restrict__ count, int* __restrict__ csr){
  int tid = blockIdx.x * 256 + threadIdx.x;
  if (tid < NE){
    int d = dst[tid];
    int s = srcp[tid];
    int sh = threadIdx.x & (SHARDS-1);
    int r = atomicAdd(&count[(d*SHARDS + sh)*16], 1);   // *16 = own 64B line
    if (r < SCAP) csr[(d << 7) + (sh << 5) + r] = s;    // overflow impossible in practice
  }
  int g = threadIdx.x & 31;
  int i = blockIdx.x * 8 + (threadIdx.x >> 5);
  if (i >= NN) return;
  float4 e = emb4[i*32 + g];
  *(ushort4*)(embh + i*DIM + g*4) =
      make_ushort4(f2bf(e.x), f2bf(e.y), f2bf(e.z), f2bf(e.w));
  float4 a = ((const float4*)v12c)[g];
  float4 b = ((const float4*)v12c)[32 + g];
  float s1 = e.x*a.x + e.y*a.y + e.z*a.z + e.w*a.w;
  float s2 = e.x*b.x + e.y*b.y + e.z*b.z + e.w*b.w;
  #pragma unroll
  for (int off = 16; off; off >>= 1){
    s1 += __shfl_down(s1, off, 32);
    s2 += __shfl_down(s2, off, 32);
  }
  if (g == 0){
    p1[i] = s1 + v12c[256];
    p2[i] = s2 + v12c[257];
  }
}

// K2: one 64-lane wave per destination node, 4 edges in flight
// (16 lanes x 16B = one 256B bf16 row each). Sharded padded-CSR row:
// flat edge index -> (shard, slot) via 3-compare select (uniform per group).
// attn computed inline (p2 is L2-resident). fp32 accum, bf16 row store.
__global__ __launch_bounds__(256) void k_gather(const int* __restrict__ count,
                       const int* __restrict__ csr,
                       const float* __restrict__ p1, const float* __restrict__ p2,
                       const unsigned short* __restrict__ embh,
                       unsigned short* __restrict__ aggh){
  int lane = threadIdx.x & 63;
  int c16 = lane & 15;                 // column slot (8 bf16 each)
  int g4 = lane >> 4;                  // edge slot 0..3
  int n = blockIdx.x * 4 + (threadIdx.x >> 6);
  if (n >= NN) return;
  int cbase = n * SHARDS * 16;
  int c0 = count[cbase];        c0 = c0 < SCAP ? c0 : SCAP;
  int c1 = count[cbase + 16];   c1 = c1 < SCAP ? c1 : SCAP;
  int c2 = count[cbase + 32];   c2 = c2 < SCAP ? c2 : SCAP;
  int c3 = count[cbase + 48];   c3 = c3 < SCAP ? c3 : SCAP;
  int o1 = c0, o2 = o1 + c1, o3 = o2 + c2, tot = o3 + c3;
  int rbase = n << 7;
  float p1n = p1[n];
  float acc[8] = {0.f,0.f,0.f,0.f,0.f,0.f,0.f,0.f};
  float dsum = 0.f;
  for (int e = g4; e < tot; e += 4){
    int slot = e < o1 ? e
             : e < o2 ? e - o1 + 32
             : e < o3 ? e - o2 + 64
             :          e - o3 + 96;
    int s = csr[rbase + slot];                       // broadcast per 16-lane group
    float sc = p1n + p2[s];                          // L2-resident (200 KB)
    sc = sc > 0.f ? sc : 0.2f * sc;
    float a = __expf(sc);
    dsum += a;
    ushort8_t v = *(const ushort8_t*)(embh + s*DIM + c16*8);  // 256B/group
    #pragma unroll
    for (int j = 0; j < 8; ++j) acc[j] += a * bf2f(v[j]);
  }
  #pragma unroll
  for (int j = 0; j < 8; ++j){
    acc[j] += __shfl_xor(acc[j], 16, 64);
    acc[j] += __shfl_xor(acc[j], 32, 64);
  }
  dsum += __shfl_xor(dsum, 16, 64);
  dsum += __shfl_xor(dsum, 32, 64);
  if (g4 == 0){
    float dinv = 1.0f / (dsum + 1e-20f);
    ushort8_t o;
    #pragma unroll
    for (int j = 0; j < 8; ++j) o[j] = f2bf(acc[j] * dinv);
    *(ushort8_t*)(aggh + n*DIM + c16*8) = o;
  }
}

// K3: MFMA GEMM h = [embh|aggh] @ Tb^T + tb, fused LayerNorm.
// Block = 4 waves x 32 nodes (two 16-node A sets share every B frag ->
// per-wave Tb L2 traffic halved); barrier-free.
__global__ __launch_bounds__(256) void k_out(const unsigned short* __restrict__ embh,
                     const unsigned short* __restrict__ aggh,
                     const unsigned short* __restrict__ Tb,
                     const float* __restrict__ tb,
                     const float* __restrict__ gamma, const float* __restrict__ beta,
                     float* __restrict__ out){
  int t = threadIdx.x;
  int w = t >> 6;
  int lane = t & 63;
  int m16 = lane & 15;
  int q = lane >> 4;                         // 0..3
  int nodebase = blockIdx.x * 128 + w * 32;
  int nA0 = nodebase + m16;
  int nA1 = nodebase + 16 + m16;
  int nA0c = (nA0 < NN) ? nA0 : 0;           // clamp loads; stores guarded
  int nA1c = (nA1 < NN) ? nA1 : 0;
  floatx4 acc[2][8];
  #pragma unroll
  for (int st = 0; st < 2; ++st)
    #pragma unroll
    for (int ct = 0; ct < 8; ++ct) acc[st][ct] = (floatx4){0.f, 0.f, 0.f, 0.f};

  #pragma unroll
  for (int kc = 0; kc < 8; ++kc){
    int k0 = kc*32 + q*8;
    const unsigned short* ap0 = (kc < 4) ? (embh + nA0c*DIM + k0)
                                         : (aggh + nA0c*DIM + (k0 - 128));
    const unsigned short* ap1 = (kc < 4) ? (embh + nA1c*DIM + k0)
                                         : (aggh + nA1c*DIM + (k0 - 128));
    short8_t afrag0 = *(const short8_t*)ap0;           // A[m][k0..k0+7]
    short8_t afrag1 = *(const short8_t*)ap1;
    #pragma unroll
    for (int ct = 0; ct < 8; ++ct){
      short8_t bfrag = *(const short8_t*)(Tb + (ct*16 + m16)*256 + k0); // B[k][j]=T[j][k]
      acc[0][ct] = __builtin_amdgcn_mfma_f32_16x16x32_bf16(afrag0, bfrag, acc[0][ct], 0, 0, 0);
      acc[1][ct] = __builtin_amdgcn_mfma_f32_16x16x32_bf16(afrag1, bfrag, acc[1][ct], 0, 0, 0);
    }
  }

  float tbv[8], gmv[8], btv[8];
  #pragma unroll
  for (int ct = 0; ct < 8; ++ct){
    int col = ct*16 + m16;
    tbv[ct] = tb[col]; gmv[ct] = gamma[col]; btv[ct] = beta[col];
  }
  #pragma unroll
  for (int st = 0; st < 2; ++st){
    #pragma unroll
    for (int r = 0; r < 4; ++r){
      int n = nodebase + st*16 + q*4 + r;    // D row = q*4 + reg
      float h[8]; float s = 0.f, ss = 0.f;
      #pragma unroll
      for (int ct = 0; ct < 8; ++ct){
        h[ct] = acc[st][ct][r] + tbv[ct];
        s += h[ct]; ss += h[ct]*h[ct];
      }
      #pragma unroll
      for (int off = 1; off < 16; off <<= 1){
        s  += __shfl_xor(s,  off, 16);
        ss += __shfl_xor(ss, off, 16);
      }
      float mu = s * (1.f/128.f);
      float var = ss * (1.f/128.f) - mu*mu;
      float rstd = rsqrtf(var + 1e-5f);
      if (n < NN){
        #pragma unroll
        for (int ct = 0; ct < 8; ++ct){
          out[n*DIM + ct*16 + m16] = (h[ct]-mu)*rstd*gmv[ct] + btv[ct];
        }
      }
    }
  }
}

extern "C" void kernel_launch(void* const* d_in, const int* in_sizes, int n_in,
                              void* d_out, int out_size, void* d_ws, size_t ws_size,
                              hipStream_t stream){
  const float* emb          = (const float*)d_in[0];
  const int*   edges        = (const int*)d_in[1];
  const float* w_weight     = (const float*)d_in[2];
  const float* w_bias       = (const float*)d_in[3];
  const float* a_weight     = (const float*)d_in[4];
  const float* a_bias       = (const float*)d_in[5];
  const float* trans_weight = (const float*)d_in[6];
  const float* trans_bias   = (const float*)d_in[7];
  const float* ln_gamma     = (const float*)d_in[8];
  const float* ln_beta      = (const float*)d_in[9];
  float* out = (float*)d_out;

  // ws layout (float offsets), ws is 256 MiB:
  // p1[50k] p2[50k] v12c[320] | count (padded, 3.2M ints) | csr (6.4M ints) |
  //   embh bf16[6.4M] | aggh bf16[6.4M] | Tb bf16[32768]
  float* ws      = (float*)d_ws;
  float* p1      = ws;
  float* p2      = ws + 50000;
  float* v12c    = ws + 100000;
  int*   count   = (int*)(ws + 100320);
  int*   csr     = (int*)(ws + 3300320);
  unsigned short* embh = (unsigned short*)(ws + 9700320);
  unsigned short* aggh = (unsigned short*)(ws + 12900320);
  unsigned short* Tb   = (unsigned short*)(ws + 16100320);

  const int* e_dst = edges;
  const int* e_src = edges + NE;

  k_setup<<<3158, 256, 0, stream>>>(w_weight, w_bias, a_weight, a_bias, v12c,
                                    (const float4*)trans_weight, (ushort4*)Tb,
                                    (int4*)count);
  k_pvec<<<(NN + 7)/8, 256, 0, stream>>>((const float4*)emb, v12c, p1, p2,
                                         embh, e_dst, e_src, count, csr);
  k_gather<<<(NN + 3)/4, 256, 0, stream>>>(count, csr, p1, p2, embh, aggh);
  k_out<<<(NN + 127)/128, 256, 0, stream>>>(embh, aggh, Tb, trans_bias,
                                            ln_gamma, ln_beta, out);
}

// Round 3
// 182.561 us; speedup vs baseline: 1.2324x; 1.1312x over previous
//
#include <hip/hip_runtime.h>
#include <hip/hip_bf16.h>

#define NN 50000
#define NE 800000
#define DIM 128
#define NBKT 196        // ceil(NN/256); bucket = dst>>8 (256 nodes/bucket)
#define BKTCAP 4608     // slots/bucket (mean 4096, +8 sigma; P(ovf)~1e-13)
#define CAP 64          // padded-CSR slots per node (lambda=16; P(ovf)~1e-15)
#define EPB 2048        // edges per phase-A block
#define NEB 391         // ceil(NE/EPB) edge blocks

typedef __attribute__((ext_vector_type(8))) short short8_t;           // 8 bf16 for MFMA
typedef __attribute__((ext_vector_type(8))) unsigned short ushort8_t; // 8 bf16 raw
typedef __attribute__((ext_vector_type(4))) float floatx4;

static __device__ inline unsigned short f2bf(float x){        // RNE float->bf16
  unsigned int u = __float_as_uint(x);
  unsigned int r = (u + 0x7FFF + ((u >> 16) & 1)) >> 16;
  return (unsigned short)r;
}
static __device__ inline float bf2f(unsigned short u){
  return __uint_as_float(((unsigned int)u) << 16);
}

// K0: heterogeneous setup. Block 0: fold W into attention vectors
// (v1 = a1^T W, v2 = a2^T W, c1 = b.a1 + a_bias, c2 = b.a2).
// Blocks 1..32: T f32 -> bf16. Blocks 33..45: zero padded gcount (3136 ints).
__global__ __launch_bounds__(256) void k_setup(const float* __restrict__ W,
                       const float* __restrict__ wb,
                       const float* __restrict__ aw, const float* __restrict__ ab,
                       float* __restrict__ v12c,
                       const float4* __restrict__ T4, ushort4* __restrict__ Tb4,
                       int* __restrict__ gcount){
  int b = blockIdx.x;
  int t = threadIdx.x;
  if (b == 0){
    __shared__ float r1[DIM], r2[DIM];
    if (t < DIM){
      float s1 = 0.f, s2 = 0.f;
      for (int j = 0; j < DIM; ++j){
        float w = W[j*DIM + t];
        s1 += aw[j] * w;
        s2 += aw[DIM + j] * w;
      }
      v12c[t] = s1;
      v12c[DIM + t] = s2;
      float bb = wb[t];
      r1[t] = bb * aw[t];
      r2[t] = bb * aw[DIM + t];
    }
    __syncthreads();
    if (t == 0){
      float a1s = 0.f, a2s = 0.f;
      for (int j = 0; j < DIM; ++j){ a1s += r1[j]; a2s += r2[j]; }
      v12c[2*DIM]   = a1s + ab[0];
      v12c[2*DIM+1] = a2s;
    }
  } else if (b <= 32){
    int i = (b-1)*256 + t;              // 8192 float4s of T
    float4 v = T4[i];
    Tb4[i] = make_ushort4(f2bf(v.x), f2bf(v.y), f2bf(v.z), f2bf(v.w));
  } else {
    int i = (b-33)*256 + t;             // NBKT*16 = 3136 padded counters
    if (i < NBKT*16) gcount[i] = 0;
  }
}

// K1 (phase A, fused): blocks 0..NEB-1 bucket the edges; blocks NEB.. do
// p1/p2 + bf16 emb copy. Edge path: LDS rank within (block,bucket), ONE
// global atomic per (block,bucket) -> 77K global atomics total (was 800K).
// Packed edge = (local_d<<16)|src (local_d<256, src<65536).
__global__ __launch_bounds__(256) void k_A(const float4* __restrict__ emb4,
                      const float* __restrict__ v12c,
                      float* __restrict__ p1, float* __restrict__ p2,
                      unsigned short* __restrict__ embh,
                      const int* __restrict__ dst, const int* __restrict__ srcp,
                      int* __restrict__ gcount, int* __restrict__ bpool){
  if (blockIdx.x < NEB){
    __shared__ int bcnt[NBKT], bbase[NBKT];
    int t = threadIdx.x;
    if (t < NBKT) bcnt[t] = 0;
    __syncthreads();
    int rnk[8], bkt[8], pk[8];
    #pragma unroll
    for (int j = 0; j < 8; ++j){
      int e = blockIdx.x * EPB + j*256 + t;
      bkt[j] = -1;
      if (e < NE){
        int d = dst[e], s = srcp[e];
        bkt[j] = d >> 8;
        pk[j] = ((d & 255) << 16) | s;
        rnk[j] = atomicAdd(&bcnt[bkt[j]], 1);     // LDS atomic
      }
    }
    __syncthreads();
    if (t < NBKT) bbase[t] = atomicAdd(&gcount[t*16], bcnt[t]);  // global, padded line
    __syncthreads();
    #pragma unroll
    for (int j = 0; j < 8; ++j){
      if (bkt[j] >= 0){
        int pos = bbase[bkt[j]] + rnk[j];
        if (pos < BKTCAP) bpool[bkt[j]*BKTCAP + pos] = pk[j];
      }
    }
    return;
  }
  // node work
  int g = threadIdx.x & 31;
  int i = (blockIdx.x - NEB) * 8 + (threadIdx.x >> 5);
  if (i >= NN) return;
  float4 e = emb4[i*32 + g];
  *(ushort4*)(embh + i*DIM + g*4) =
      make_ushort4(f2bf(e.x), f2bf(e.y), f2bf(e.z), f2bf(e.w));
  float4 a = ((const float4*)v12c)[g];
  float4 b = ((const float4*)v12c)[32 + g];
  float s1 = e.x*a.x + e.y*a.y + e.z*a.z + e.w*a.w;
  float s2 = e.x*b.x + e.y*b.y + e.z*b.z + e.w*b.w;
  #pragma unroll
  for (int off = 16; off; off >>= 1){
    s1 += __shfl_down(s1, off, 32);
    s2 += __shfl_down(s2, off, 32);
  }
  if (g == 0){
    p1[i] = s1 + v12c[256];
    p2[i] = s2 + v12c[257];
  }
}

// K2 (phase B): one block per bucket. Coalesced read of the bucket's packed
// edges, exact per-node rank via 256 LDS counters (ZERO global atomics),
// write padded per-node CSR (64KB window -> L2-local) + dense count[n].
__global__ __launch_bounds__(256) void k_B(const int* __restrict__ gcount,
                      const int* __restrict__ bpool,
                      int* __restrict__ count, int* __restrict__ csr){
  __shared__ int cnt[256];
  int b = blockIdx.x, t = threadIdx.x;
  cnt[t] = 0;
  __syncthreads();
  int m = gcount[b*16]; if (m > BKTCAP) m = BKTCAP;
  int base = b * BKTCAP;
  int rnk[18], pkv[18];
  #pragma unroll
  for (int it = 0; it < 18; ++it){     // 18*256 = 4608 = BKTCAP
    int e = it*256 + t;
    pkv[it] = -1;
    if (e < m){
      int pk = bpool[base + e];
      pkv[it] = pk;
      rnk[it] = atomicAdd(&cnt[(pk >> 16) & 255], 1);   // LDS atomic
    }
  }
  __syncthreads();
  int n = b*256 + t;
  if (n < NN){ int c = cnt[t]; count[n] = c < CAP ? c : CAP; }
  #pragma unroll
  for (int it = 0; it < 18; ++it){
    if (pkv[it] >= 0 && rnk[it] < CAP){
      int d = b*256 + ((pkv[it] >> 16) & 255);
      csr[(d << 6) + rnk[it]] = pkv[it] & 0xFFFF;
    }
  }
}

// K3: one 64-lane wave per destination node, 4 edges in flight
// (16 lanes x 16B = one 256B bf16 row each). Contiguous padded row:
// base = n<<6, cnt = count[n] (pre-capped). attn computed inline
// (p2 is L2-resident). fp32 accum, bf16 row store.
__global__ __launch_bounds__(256) void k_gather(const int* __restrict__ count,
                       const int* __restrict__ csr,
                       const float* __restrict__ p1, const float* __restrict__ p2,
                       const unsigned short* __restrict__ embh,
                       unsigned short* __restrict__ aggh){
  int lane = threadIdx.x & 63;
  int c16 = lane & 15;                 // column slot (8 bf16 each)
  int g4 = lane >> 4;                  // edge slot 0..3
  int n = blockIdx.x * 4 + (threadIdx.x >> 6);
  if (n >= NN) return;
  int cnt = count[n];
  int s0 = n << 6;
  float p1n = p1[n];
  float acc[8] = {0.f,0.f,0.f,0.f,0.f,0.f,0.f,0.f};
  float dsum = 0.f;
  for (int e = g4; e < cnt; e += 4){
    int s = csr[s0 + e];                             // broadcast per 16-lane group
    float sc = p1n + p2[s];                          // L2-resident (200 KB)
    sc = sc > 0.f ? sc : 0.2f * sc;
    float a = __expf(sc);
    dsum += a;
    ushort8_t v = *(const ushort8_t*)(embh + s*DIM + c16*8);  // 256B/group
    #pragma unroll
    for (int j = 0; j < 8; ++j) acc[j] += a * bf2f(v[j]);
  }
  #pragma unroll
  for (int j = 0; j < 8; ++j){
    acc[j] += __shfl_xor(acc[j], 16, 64);
    acc[j] += __shfl_xor(acc[j], 32, 64);
  }
  dsum += __shfl_xor(dsum, 16, 64);
  dsum += __shfl_xor(dsum, 32, 64);
  if (g4 == 0){
    float dinv = 1.0f / (dsum + 1e-20f);
    ushort8_t o;
    #pragma unroll
    for (int j = 0; j < 8; ++j) o[j] = f2bf(acc[j] * dinv);
    *(ushort8_t*)(aggh + n*DIM + c16*8) = o;
  }
}

// K4: MFMA GEMM h = [embh|aggh] @ Tb^T + tb, fused LayerNorm.
// Block = 4 waves x 32 nodes (two 16-node A sets share every B frag ->
// per-wave Tb L2 traffic halved); barrier-free.
__global__ __launch_bounds__(256) void k_out(const unsigned short* __restrict__ embh,
                     const unsigned short* __restrict__ aggh,
                     const unsigned short* __restrict__ Tb,
                     const float* __restrict__ tb,
                     const float* __restrict__ gamma, const float* __restrict__ beta,
                     float* __restrict__ out){
  int t = threadIdx.x;
  int w = t >> 6;
  int lane = t & 63;
  int m16 = lane & 15;
  int q = lane >> 4;                         // 0..3
  int nodebase = blockIdx.x * 128 + w * 32;
  int nA0 = nodebase + m16;
  int nA1 = nodebase + 16 + m16;
  int nA0c = (nA0 < NN) ? nA0 : 0;           // clamp loads; stores guarded
  int nA1c = (nA1 < NN) ? nA1 : 0;
  floatx4 acc[2][8];
  #pragma unroll
  for (int st = 0; st < 2; ++st)
    #pragma unroll
    for (int ct = 0; ct < 8; ++ct) acc[st][ct] = (floatx4){0.f, 0.f, 0.f, 0.f};

  #pragma unroll
  for (int kc = 0; kc < 8; ++kc){
    int k0 = kc*32 + q*8;
    const unsigned short* ap0 = (kc < 4) ? (embh + nA0c*DIM + k0)
                                         : (aggh + nA0c*DIM + (k0 - 128));
    const unsigned short* ap1 = (kc < 4) ? (embh + nA1c*DIM + k0)
                                         : (aggh + nA1c*DIM + (k0 - 128));
    short8_t afrag0 = *(const short8_t*)ap0;           // A[m][k0..k0+7]
    short8_t afrag1 = *(const short8_t*)ap1;
    #pragma unroll
    for (int ct = 0; ct < 8; ++ct){
      short8_t bfrag = *(const short8_t*)(Tb + (ct*16 + m16)*256 + k0); // B[k][j]=T[j][k]
      acc[0][ct] = __builtin_amdgcn_mfma_f32_16x16x32_bf16(afrag0, bfrag, acc[0][ct], 0, 0, 0);
      acc[1][ct] = __builtin_amdgcn_mfma_f32_16x16x32_bf16(afrag1, bfrag, acc[1][ct], 0, 0, 0);
    }
  }

  float tbv[8], gmv[8], btv[8];
  #pragma unroll
  for (int ct = 0; ct < 8; ++ct){
    int col = ct*16 + m16;
    tbv[ct] = tb[col]; gmv[ct] = gamma[col]; btv[ct] = beta[col];
  }
  #pragma unroll
  for (int st = 0; st < 2; ++st){
    #pragma unroll
    for (int r = 0; r < 4; ++r){
      int n = nodebase + st*16 + q*4 + r;    // D row = q*4 + reg
      float h[8]; float s = 0.f, ss = 0.f;
      #pragma unroll
      for (int ct = 0; ct < 8; ++ct){
        h[ct] = acc[st][ct][r] + tbv[ct];
        s += h[ct]; ss += h[ct]*h[ct];
      }
      #pragma unroll
      for (int off = 1; off < 16; off <<= 1){
        s  += __shfl_xor(s,  off, 16);
        ss += __shfl_xor(ss, off, 16);
      }
      float mu = s * (1.f/128.f);
      float var = ss * (1.f/128.f) - mu*mu;
      float rstd = rsqrtf(var + 1e-5f);
      if (n < NN){
        #pragma unroll
        for (int ct = 0; ct < 8; ++ct){
          out[n*DIM + ct*16 + m16] = (h[ct]-mu)*rstd*gmv[ct] + btv[ct];
        }
      }
    }
  }
}

extern "C" void kernel_launch(void* const* d_in, const int* in_sizes, int n_in,
                              void* d_out, int out_size, void* d_ws, size_t ws_size,
                              hipStream_t stream){
  const float* emb          = (const float*)d_in[0];
  const int*   edges        = (const int*)d_in[1];
  const float* w_weight     = (const float*)d_in[2];
  const float* w_bias       = (const float*)d_in[3];
  const float* a_weight     = (const float*)d_in[4];
  const float* a_bias       = (const float*)d_in[5];
  const float* trans_weight = (const float*)d_in[6];
  const float* trans_bias   = (const float*)d_in[7];
  const float* ln_gamma     = (const float*)d_in[8];
  const float* ln_beta      = (const float*)d_in[9];
  float* out = (float*)d_out;

  // ws layout (float offsets), ws is 256 MiB:
  // p1[50k] p2[50k] v12c[320] | count[50k] | gcount (196 padded lines, 3136) |
  //   csr (3.2M ints) | bpool (196*4608 ints) | embh bf16[6.4M] |
  //   aggh bf16[6.4M] | Tb bf16[32768]
  float* ws      = (float*)d_ws;
  float* p1      = ws;
  float* p2      = ws + 50000;
  float* v12c    = ws + 100000;
  int*   count   = (int*)(ws + 100320);
  int*   gcount  = (int*)(ws + 150320);
  int*   csr     = (int*)(ws + 153472);
  int*   bpool   = (int*)(ws + 3353472);
  unsigned short* embh = (unsigned short*)(ws + 4256640);
  unsigned short* aggh = (unsigned short*)(ws + 7456640);
  unsigned short* Tb   = (unsigned short*)(ws + 10656640);

  const int* e_dst = edges;
  const int* e_src = edges + NE;

  k_setup<<<46, 256, 0, stream>>>(w_weight, w_bias, a_weight, a_bias, v12c,
                                  (const float4*)trans_weight, (ushort4*)Tb, gcount);
  k_A<<<NEB + (NN + 7)/8, 256, 0, stream>>>((const float4*)emb, v12c, p1, p2,
                                            embh, e_dst, e_src, gcount, bpool);
  k_B<<<NBKT, 256, 0, stream>>>(gcount, bpool, count, csr);
  k_gather<<<(NN + 3)/4, 256, 0, stream>>>(count, csr, p1, p2, embh, aggh);
  k_out<<<(NN + 127)/128, 256, 0, stream>>>(embh, aggh, Tb, trans_bias,
                                            ln_gamma, ln_beta, out);
}

// Round 5
// 178.511 us; speedup vs baseline: 1.2604x; 1.0227x over previous
//
#include <hip/hip_runtime.h>
#include <hip/hip_bf16.h>

#define NN 50000
#define NE 800000
#define DIM 128
#define NBKT 196        // ceil(NN/256); bucket = dst>>8 (256 nodes/bucket)
#define BKTCAP 4608     // slots/bucket (mean 4096, +8 sigma; P(ovf)~1e-13)
#define CAP 64          // padded-CSR slots per node (lambda=16; P(ovf)~1e-15)
#define EPB 2048        // edges per phase-A block
#define NEB 391         // ceil(NE/EPB) edge blocks

typedef __attribute__((ext_vector_type(8))) short short8_t;           // 8 bf16 for MFMA
typedef __attribute__((ext_vector_type(8))) unsigned short ushort8_t; // 8 bf16 raw
typedef __attribute__((ext_vector_type(4))) float floatx4;

static __device__ inline unsigned short f2bf(float x){        // RNE float->bf16
  unsigned int u = __float_as_uint(x);
  unsigned int r = (u + 0x7FFF + ((u >> 16) & 1)) >> 16;
  return (unsigned short)r;
}
static __device__ inline float bf2f(unsigned short u){
  return __uint_as_float(((unsigned int)u) << 16);
}

// K0: heterogeneous setup. Block 0: fold W into attention vectors
// (v1 = a1^T W, v2 = a2^T W, c1 = b.a1 + a_bias, c2 = b.a2).
// Blocks 1..32: T f32 -> bf16. Blocks 33..45: zero padded gcount (3136 ints).
__global__ __launch_bounds__(256) void k_setup(const float* __restrict__ W,
                       const float* __restrict__ wb,
                       const float* __restrict__ aw, const float* __restrict__ ab,
                       float* __restrict__ v12c,
                       const float4* __restrict__ T4, ushort4* __restrict__ Tb4,
                       int* __restrict__ gcount){
  int b = blockIdx.x;
  int t = threadIdx.x;
  if (b == 0){
    __shared__ float r1[DIM], r2[DIM];
    if (t < DIM){
      float s1 = 0.f, s2 = 0.f;
      for (int j = 0; j < DIM; ++j){
        float w = W[j*DIM + t];
        s1 += aw[j] * w;
        s2 += aw[DIM + j] * w;
      }
      v12c[t] = s1;
      v12c[DIM + t] = s2;
      float bb = wb[t];
      r1[t] = bb * aw[t];
      r2[t] = bb * aw[DIM + t];
    }
    __syncthreads();
    if (t == 0){
      float a1s = 0.f, a2s = 0.f;
      for (int j = 0; j < DIM; ++j){ a1s += r1[j]; a2s += r2[j]; }
      v12c[2*DIM]   = a1s + ab[0];
      v12c[2*DIM+1] = a2s;
    }
  } else if (b <= 32){
    int i = (b-1)*256 + t;              // 8192 float4s of T
    float4 v = T4[i];
    Tb4[i] = make_ushort4(f2bf(v.x), f2bf(v.y), f2bf(v.z), f2bf(v.w));
  } else {
    int i = (b-33)*256 + t;             // NBKT*16 = 3136 padded counters
    if (i < NBKT*16) gcount[i] = 0;
  }
}

// K1 (phase A, fused): blocks 0..NEB-1 bucket the edges; blocks NEB.. do
// p1/p2 + bf16 emb copy. Edge path: LDS rank within (block,bucket), ONE
// global atomic per (block,bucket) -> 77K global atomics total (was 800K).
// Packed edge = (local_d<<16)|src (local_d<256, src<65536).
__global__ __launch_bounds__(256) void k_A(const float4* __restrict__ emb4,
                      const float* __restrict__ v12c,
                      float* __restrict__ p1, float* __restrict__ p2,
                      unsigned short* __restrict__ embh,
                      const int* __restrict__ dst, const int* __restrict__ srcp,
                      int* __restrict__ gcount, int* __restrict__ bpool){
  if (blockIdx.x < NEB){
    __shared__ int bcnt[NBKT], bbase[NBKT];
    int t = threadIdx.x;
    if (t < NBKT) bcnt[t] = 0;
    __syncthreads();
    int rnk[8], bkt[8], pk[8];
    #pragma unroll
    for (int j = 0; j < 8; ++j){
      int e = blockIdx.x * EPB + j*256 + t;
      bkt[j] = -1;
      if (e < NE){
        int d = dst[e], s = srcp[e];
        bkt[j] = d >> 8;
        pk[j] = ((d & 255) << 16) | s;
        rnk[j] = atomicAdd(&bcnt[bkt[j]], 1);     // LDS atomic
      }
    }
    __syncthreads();
    if (t < NBKT) bbase[t] = atomicAdd(&gcount[t*16], bcnt[t]);  // global, padded line
    __syncthreads();
    #pragma unroll
    for (int j = 0; j < 8; ++j){
      if (bkt[j] >= 0){
        int pos = bbase[bkt[j]] + rnk[j];
        if (pos < BKTCAP) bpool[bkt[j]*BKTCAP + pos] = pk[j];
      }
    }
    return;
  }
  // node work
  int g = threadIdx.x & 31;
  int i = (blockIdx.x - NEB) * 8 + (threadIdx.x >> 5);
  if (i >= NN) return;
  float4 e = emb4[i*32 + g];
  *(ushort4*)(embh + i*DIM + g*4) =
      make_ushort4(f2bf(e.x), f2bf(e.y), f2bf(e.z), f2bf(e.w));
  float4 a = ((const float4*)v12c)[g];
  float4 b = ((const float4*)v12c)[32 + g];
  float s1 = e.x*a.x + e.y*a.y + e.z*a.z + e.w*a.w;
  float s2 = e.x*b.x + e.y*b.y + e.z*b.z + e.w*b.w;
  #pragma unroll
  for (int off = 16; off; off >>= 1){
    s1 += __shfl_down(s1, off, 32);
    s2 += __shfl_down(s2, off, 32);
  }
  if (g == 0){
    p1[i] = s1 + v12c[256];
    p2[i] = s2 + v12c[257];
  }
}

// K2 (phase B): one block per bucket. Coalesced read of the bucket's packed
// edges, exact per-node rank via 256 LDS counters (ZERO global atomics),
// write padded per-node CSR (64KB window -> L2-local) + dense count[n].
__global__ __launch_bounds__(256) void k_B(const int* __restrict__ gcount,
                      const int* __restrict__ bpool,
                      int* __restrict__ count, int* __restrict__ csr){
  __shared__ int cnt[256];
  int b = blockIdx.x, t = threadIdx.x;
  cnt[t] = 0;
  __syncthreads();
  int m = gcount[b*16]; if (m > BKTCAP) m = BKTCAP;
  int base = b * BKTCAP;
  int rnk[18], pkv[18];
  #pragma unroll
  for (int it = 0; it < 18; ++it){     // 18*256 = 4608 = BKTCAP
    int e = it*256 + t;
    pkv[it] = -1;
    if (e < m){
      int pk = bpool[base + e];
      pkv[it] = pk;
      rnk[it] = atomicAdd(&cnt[(pk >> 16) & 255], 1);   // LDS atomic
    }
  }
  __syncthreads();
  int n = b*256 + t;
  if (n < NN){ int c = cnt[t]; count[n] = c < CAP ? c : CAP; }
  #pragma unroll
  for (int it = 0; it < 18; ++it){
    if (pkv[it] >= 0 && rnk[it] < CAP){
      int d = b*256 + ((pkv[it] >> 16) & 255);
      csr[(d << 6) + rnk[it]] = pkv[it] & 0xFFFF;
    }
  }
}

// K3: one 64-lane wave per destination node (16 lanes x 16B = one 256B bf16
// row per edge slot). Round-3 structure (group-uniform broadcast csr reads,
// known correct) + 2-DEEP edge pipelining: edges e and e+4 per iteration
// issue two independent load chains back-to-back, halving exposed latency.
// Tail edge's row load guarded (poison bytes are NaN-able bf16).
__global__ __launch_bounds__(256) void k_gather(const int* __restrict__ count,
                       const int* __restrict__ csr,
                       const float* __restrict__ p1, const float* __restrict__ p2,
                       const unsigned short* __restrict__ embh,
                       unsigned short* __restrict__ aggh){
  int lane = threadIdx.x & 63;
  int c16 = lane & 15;                 // column slot (8 bf16 each)
  int g4 = lane >> 4;                  // edge slot 0..3
  int n = blockIdx.x * 4 + (threadIdx.x >> 6);
  if (n >= NN) return;
  int cnt = count[n];                  // pre-capped at 64
  int s0 = n << 6;
  float p1n = p1[n];
  float acc[8] = {0.f,0.f,0.f,0.f,0.f,0.f,0.f,0.f};
  float dsum = 0.f;
  for (int e = g4; e < cnt; e += 8){
    int sA = csr[s0 + e];                            // broadcast per 16-lane group
    int eB = e + 4;
    int sB = (eB < cnt) ? csr[s0 + eB] : -1;
    float scA = p1n + p2[sA];                        // L2-resident (200 KB)
    scA = scA > 0.f ? scA : 0.2f * scA;
    float aA = __expf(scA);
    dsum += aA;
    ushort8_t vA = *(const ushort8_t*)(embh + sA*DIM + c16*8);  // 256B/group
    #pragma unroll
    for (int j = 0; j < 8; ++j) acc[j] += aA * bf2f(vA[j]);
    if (sB >= 0){
      float scB = p1n + p2[sB];
      scB = scB > 0.f ? scB : 0.2f * scB;
      float aB = __expf(scB);
      dsum += aB;
      ushort8_t vB = *(const ushort8_t*)(embh + sB*DIM + c16*8);
      #pragma unroll
      for (int j = 0; j < 8; ++j) acc[j] += aB * bf2f(vB[j]);
    }
  }
  #pragma unroll
  for (int j = 0; j < 8; ++j){
    acc[j] += __shfl_xor(acc[j], 16, 64);
    acc[j] += __shfl_xor(acc[j], 32, 64);
  }
  dsum += __shfl_xor(dsum, 16, 64);
  dsum += __shfl_xor(dsum, 32, 64);
  if (g4 == 0){
    float dinv = 1.0f / (dsum + 1e-20f);
    ushort8_t o;
    #pragma unroll
    for (int j = 0; j < 8; ++j) o[j] = f2bf(acc[j] * dinv);
    *(ushort8_t*)(aggh + n*DIM + c16*8) = o;
  }
}

// K4: MFMA GEMM h = [embh|aggh] @ Tb^T + tb, fused LayerNorm.
// Block = 4 waves x 32 nodes (two 16-node A sets share every B frag ->
// per-wave Tb L2 traffic halved); barrier-free.
__global__ __launch_bounds__(256) void k_out(const unsigned short* __restrict__ embh,
                     const unsigned short* __restrict__ aggh,
                     const unsigned short* __restrict__ Tb,
                     const float* __restrict__ tb,
                     const float* __restrict__ gamma, const float* __restrict__ beta,
                     float* __restrict__ out){
  int t = threadIdx.x;
  int w = t >> 6;
  int lane = t & 63;
  int m16 = lane & 15;
  int q = lane >> 4;                         // 0..3
  int nodebase = blockIdx.x * 128 + w * 32;
  int nA0 = nodebase + m16;
  int nA1 = nodebase + 16 + m16;
  int nA0c = (nA0 < NN) ? nA0 : 0;           // clamp loads; stores guarded
  int nA1c = (nA1 < NN) ? nA1 : 0;
  floatx4 acc[2][8];
  #pragma unroll
  for (int st = 0; st < 2; ++st)
    #pragma unroll
    for (int ct = 0; ct < 8; ++ct) acc[st][ct] = (floatx4){0.f, 0.f, 0.f, 0.f};

  #pragma unroll
  for (int kc = 0; kc < 8; ++kc){
    int k0 = kc*32 + q*8;
    const unsigned short* ap0 = (kc < 4) ? (embh + nA0c*DIM + k0)
                                         : (aggh + nA0c*DIM + (k0 - 128));
    const unsigned short* ap1 = (kc < 4) ? (embh + nA1c*DIM + k0)
                                         : (aggh + nA1c*DIM + (k0 - 128));
    short8_t afrag0 = *(const short8_t*)ap0;           // A[m][k0..k0+7]
    short8_t afrag1 = *(const short8_t*)ap1;
    #pragma unroll
    for (int ct = 0; ct < 8; ++ct){
      short8_t bfrag = *(const short8_t*)(Tb + (ct*16 + m16)*256 + k0); // B[k][j]=T[j][k]
      acc[0][ct] = __builtin_amdgcn_mfma_f32_16x16x32_bf16(afrag0, bfrag, acc[0][ct], 0, 0, 0);
      acc[1][ct] = __builtin_amdgcn_mfma_f32_16x16x32_bf16(afrag1, bfrag, acc[1][ct], 0, 0, 0);
    }
  }

  float tbv[8], gmv[8], btv[8];
  #pragma unroll
  for (int ct = 0; ct < 8; ++ct){
    int col = ct*16 + m16;
    tbv[ct] = tb[col]; gmv[ct] = gamma[col]; btv[ct] = beta[col];
  }
  #pragma unroll
  for (int st = 0; st < 2; ++st){
    #pragma unroll
    for (int r = 0; r < 4; ++r){
      int n = nodebase + st*16 + q*4 + r;    // D row = q*4 + reg
      float h[8]; float s = 0.f, ss = 0.f;
      #pragma unroll
      for (int ct = 0; ct < 8; ++ct){
        h[ct] = acc[st][ct][r] + tbv[ct];
        s += h[ct]; ss += h[ct]*h[ct];
      }
      #pragma unroll
      for (int off = 1; off < 16; off <<= 1){
        s  += __shfl_xor(s,  off, 16);
        ss += __shfl_xor(ss, off, 16);
      }
      float mu = s * (1.f/128.f);
      float var = ss * (1.f/128.f) - mu*mu;
      float rstd = rsqrtf(var + 1e-5f);
      if (n < NN){
        #pragma unroll
        for (int ct = 0; ct < 8; ++ct){
          out[n*DIM + ct*16 + m16] = (h[ct]-mu)*rstd*gmv[ct] + btv[ct];
        }
      }
    }
  }
}

extern "C" void kernel_launch(void* const* d_in, const int* in_sizes, int n_in,
                              void* d_out, int out_size, void* d_ws, size_t ws_size,
                              hipStream_t stream){
  const float* emb          = (const float*)d_in[0];
  const int*   edges        = (const int*)d_in[1];
  const float* w_weight     = (const float*)d_in[2];
  const float* w_bias       = (const float*)d_in[3];
  const float* a_weight     = (const float*)d_in[4];
  const float* a_bias       = (const float*)d_in[5];
  const float* trans_weight = (const float*)d_in[6];
  const float* trans_bias   = (const float*)d_in[7];
  const float* ln_gamma     = (const float*)d_in[8];
  const float* ln_beta      = (const float*)d_in[9];
  float* out = (float*)d_out;

  // ws layout (float offsets), ws is 256 MiB:
  // p1[50k] p2[50k] v12c[320] | count[50k] | gcount (196 padded lines, 3136) |
  //   csr (3.2M ints) | bpool (196*4608 ints) | embh bf16[6.4M] |
  //   aggh bf16[6.4M] | Tb bf16[32768]
  float* ws      = (float*)d_ws;
  float* p1      = ws;
  float* p2      = ws + 50000;
  float* v12c    = ws + 100000;
  int*   count   = (int*)(ws + 100320);
  int*   gcount  = (int*)(ws + 150320);
  int*   csr     = (int*)(ws + 153472);
  int*   bpool   = (int*)(ws + 3353472);
  unsigned short* embh = (unsigned short*)(ws + 4256640);
  unsigned short* aggh = (unsigned short*)(ws + 7456640);
  unsigned short* Tb   = (unsigned short*)(ws + 10656640);

  const int* e_dst = edges;
  const int* e_src = edges + NE;

  k_setup<<<46, 256, 0, stream>>>(w_weight, w_bias, a_weight, a_bias, v12c,
                                  (const float4*)trans_weight, (ushort4*)Tb, gcount);
  k_A<<<NEB + (NN + 7)/8, 256, 0, stream>>>((const float4*)emb, v12c, p1, p2,
                                            embh, e_dst, e_src, gcount, bpool);
  k_B<<<NBKT, 256, 0, stream>>>(gcount, bpool, count, csr);
  k_gather<<<(NN + 3)/4, 256, 0, stream>>>(count, csr, p1, p2, embh, aggh);
  k_out<<<(NN + 127)/128, 256, 0, stream>>>(embh, aggh, Tb, trans_bias,
                                            ln_gamma, ln_beta, out);
}

// Round 6
// 176.243 us; speedup vs baseline: 1.2766x; 1.0129x over previous
//
#include <hip/hip_runtime.h>
#include <hip/hip_bf16.h>

#define NN 50000
#define NE 800000
#define DIM 128
#define NBKT 196        // ceil(50000/256); bucket = dst>>8 (256 nodes/bucket)
#define BKTCAP 4608     // slots/bucket (mean 4096, +8 sigma; P(ovf)~1e-13)
#define CAP 64          // padded-CSR slots per node (lambda=16; P(ovf)~1e-15)
#define EPB 2048        // edges per phase-A block
#define NEB 391         // ceil(NE/EPB) edge blocks

typedef __attribute__((ext_vector_type(8))) short short8_t;           // 8 bf16 for MFMA
typedef __attribute__((ext_vector_type(8))) unsigned short ushort8_t; // 8 bf16 raw
typedef __attribute__((ext_vector_type(4))) float floatx4;

static __device__ inline unsigned short f2bf(float x){        // RNE float->bf16
  unsigned int u = __float_as_uint(x);
  unsigned int r = (u + 0x7FFF + ((u >> 16) & 1)) >> 16;
  return (unsigned short)r;
}
static __device__ inline float bf2f(unsigned short u){
  return __uint_as_float(((unsigned int)u) << 16);
}

// K0: heterogeneous setup. Block 0: fold W into attention vectors
// (v1 = a1^T W, v2 = a2^T W, c1 = b.a1 + a_bias, c2 = b.a2).
// Blocks 1..32: T f32 -> bf16. Blocks 33..45: zero padded gcount (3136 ints).
__global__ __launch_bounds__(256) void k_setup(const float* __restrict__ W,
                       const float* __restrict__ wb,
                       const float* __restrict__ aw, const float* __restrict__ ab,
                       float* __restrict__ v12c,
                       const float4* __restrict__ T4, ushort4* __restrict__ Tb4,
                       int* __restrict__ gcount){
  int b = blockIdx.x;
  int t = threadIdx.x;
  if (b == 0){
    __shared__ float r1[DIM], r2[DIM];
    if (t < DIM){
      float s1 = 0.f, s2 = 0.f;
      for (int j = 0; j < DIM; ++j){
        float w = W[j*DIM + t];
        s1 += aw[j] * w;
        s2 += aw[DIM + j] * w;
      }
      v12c[t] = s1;
      v12c[DIM + t] = s2;
      float bb = wb[t];
      r1[t] = bb * aw[t];
      r2[t] = bb * aw[DIM + t];
    }
    __syncthreads();
    if (t == 0){
      float a1s = 0.f, a2s = 0.f;
      for (int j = 0; j < DIM; ++j){ a1s += r1[j]; a2s += r2[j]; }
      v12c[2*DIM]   = a1s + ab[0];
      v12c[2*DIM+1] = a2s;
    }
  } else if (b <= 32){
    int i = (b-1)*256 + t;              // 8192 float4s of T
    float4 v = T4[i];
    Tb4[i] = make_ushort4(f2bf(v.x), f2bf(v.y), f2bf(v.z), f2bf(v.w));
  } else {
    int i = (b-33)*256 + t;             // NBKT*16 = 3136 padded counters
    if (i < NBKT*16) gcount[i] = 0;
  }
}

// K1 (phase A, fused): blocks 0..NEB-1 bucket the edges; blocks NEB.. do
// p1/p2 + bf16 emb copy. Edge path: LDS rank within (block,bucket), ONE
// global atomic per (block,bucket) -> 77K global atomics total (was 800K).
// Packed edge = (local_d<<16)|src (local_d<256, src<65536).
__global__ __launch_bounds__(256) void k_A(const float4* __restrict__ emb4,
                      const float* __restrict__ v12c,
                      float* __restrict__ p1, float* __restrict__ p2,
                      unsigned short* __restrict__ embh,
                      const int* __restrict__ dst, const int* __restrict__ srcp,
                      int* __restrict__ gcount, int* __restrict__ bpool){
  if (blockIdx.x < NEB){
    __shared__ int bcnt[NBKT], bbase[NBKT];
    int t = threadIdx.x;
    if (t < NBKT) bcnt[t] = 0;
    __syncthreads();
    int rnk[8], bkt[8], pk[8];
    #pragma unroll
    for (int j = 0; j < 8; ++j){
      int e = blockIdx.x * EPB + j*256 + t;
      bkt[j] = -1;
      if (e < NE){
        int d = dst[e], s = srcp[e];
        bkt[j] = d >> 8;
        pk[j] = ((d & 255) << 16) | s;
        rnk[j] = atomicAdd(&bcnt[bkt[j]], 1);     // LDS atomic
      }
    }
    __syncthreads();
    if (t < NBKT) bbase[t] = atomicAdd(&gcount[t*16], bcnt[t]);  // global, padded line
    __syncthreads();
    #pragma unroll
    for (int j = 0; j < 8; ++j){
      if (bkt[j] >= 0){
        int pos = bbase[bkt[j]] + rnk[j];
        if (pos < BKTCAP) bpool[bkt[j]*BKTCAP + pos] = pk[j];
      }
    }
    return;
  }
  // node work
  int g = threadIdx.x & 31;
  int i = (blockIdx.x - NEB) * 8 + (threadIdx.x >> 5);
  if (i >= NN) return;
  float4 e = emb4[i*32 + g];
  *(ushort4*)(embh + i*DIM + g*4) =
      make_ushort4(f2bf(e.x), f2bf(e.y), f2bf(e.z), f2bf(e.w));
  float4 a = ((const float4*)v12c)[g];
  float4 b = ((const float4*)v12c)[32 + g];
  float s1 = e.x*a.x + e.y*a.y + e.z*a.z + e.w*a.w;
  float s2 = e.x*b.x + e.y*b.y + e.z*b.z + e.w*b.w;
  #pragma unroll
  for (int off = 16; off; off >>= 1){
    s1 += __shfl_down(s1, off, 32);
    s2 += __shfl_down(s2, off, 32);
  }
  if (g == 0){
    p1[i] = s1 + v12c[256];
    p2[i] = s2 + v12c[257];
  }
}

// K2 (phase B): one block per bucket. Coalesced read of the bucket's packed
// edges, exact per-node rank via 256 LDS counters (ZERO global atomics),
// write padded per-node CSR (64KB window -> L2-local) + dense count[n].
__global__ __launch_bounds__(256) void k_B(const int* __restrict__ gcount,
                      const int* __restrict__ bpool,
                      int* __restrict__ count, int* __restrict__ csr){
  __shared__ int cnt[256];
  int b = blockIdx.x, t = threadIdx.x;
  cnt[t] = 0;
  __syncthreads();
  int m = gcount[b*16]; if (m > BKTCAP) m = BKTCAP;
  int base = b * BKTCAP;
  int rnk[18], pkv[18];
  #pragma unroll
  for (int it = 0; it < 18; ++it){     // 18*256 = 4608 = BKTCAP
    int e = it*256 + t;
    pkv[it] = -1;
    if (e < m){
      int pk = bpool[base + e];
      pkv[it] = pk;
      rnk[it] = atomicAdd(&cnt[(pk >> 16) & 255], 1);   // LDS atomic
    }
  }
  __syncthreads();
  int n = b*256 + t;
  if (n < NN){ int c = cnt[t]; count[n] = c < CAP ? c : CAP; }
  #pragma unroll
  for (int it = 0; it < 18; ++it){
    if (pkv[it] >= 0 && rnk[it] < CAP){
      int d = b*256 + ((pkv[it] >> 16) & 255);
      csr[(d << 6) + rnk[it]] = pkv[it] & 0xFFFF;
    }
  }
}

// K3: one 64-lane wave per destination node (16 lanes x 16B = one 256B bf16
// row per edge slot). BRANCH-FREE 4-deep pipeline: edges e,e+4,e+8,e+12 per
// iteration; inactive slots clamp to source 0 (always-valid memory) with
// weight forced to 0, so all 4 csr reads + 4 p2 reads + 4 row loads issue
// unconditionally with no exec-mask control flow. Typical node (cnt~16):
// the whole neighborhood is in flight in one iteration.
__global__ __launch_bounds__(256) void k_gather(const int* __restrict__ count,
                       const int* __restrict__ csr,
                       const float* __restrict__ p1, const float* __restrict__ p2,
                       const unsigned short* __restrict__ embh,
                       unsigned short* __restrict__ aggh){
  int lane = threadIdx.x & 63;
  int c16 = lane & 15;                 // column slot (8 bf16 each)
  int g4 = lane >> 4;                  // edge slot 0..3
  int n = blockIdx.x * 4 + (threadIdx.x >> 6);
  if (n >= NN) return;
  int cnt = count[n];                  // pre-capped at 64
  int s0 = n << 6;
  float p1n = p1[n];
  float acc[8] = {0.f,0.f,0.f,0.f,0.f,0.f,0.f,0.f};
  float dsum = 0.f;
  for (int e = g4; e < cnt; e += 16){
    int e1 = e + 4, e2 = e + 8, e3 = e + 12;
    // clamped csr reads: slot (s0+e) for e<cnt is valid; inactive -> slot s0
    int sa = csr[s0 + e];
    int sb = csr[e1 < cnt ? s0 + e1 : s0];
    int sc = csr[e2 < cnt ? s0 + e2 : s0];
    int sd = csr[e3 < cnt ? s0 + e3 : s0];
    float fa = p1n + p2[sa];
    float fb = p1n + p2[sb];
    float fc = p1n + p2[sc];
    float fd = p1n + p2[sd];
    fa = fa > 0.f ? fa : 0.2f * fa;
    fb = fb > 0.f ? fb : 0.2f * fb;
    fc = fc > 0.f ? fc : 0.2f * fc;
    fd = fd > 0.f ? fd : 0.2f * fd;
    float aa = __expf(fa);
    float ab_ = (e1 < cnt) ? __expf(fb) : 0.f;
    float ac = (e2 < cnt) ? __expf(fc) : 0.f;
    float ad = (e3 < cnt) ? __expf(fd) : 0.f;
    dsum += aa + ab_ + ac + ad;
    const ushort8_t va = *(const ushort8_t*)(embh + sa*DIM + c16*8);  // 256B/group
    const ushort8_t vb = *(const ushort8_t*)(embh + sb*DIM + c16*8);
    const ushort8_t vc = *(const ushort8_t*)(embh + sc*DIM + c16*8);
    const ushort8_t vd = *(const ushort8_t*)(embh + sd*DIM + c16*8);
    #pragma unroll
    for (int j = 0; j < 8; ++j){
      acc[j] += aa * bf2f(va[j]) + ab_ * bf2f(vb[j])
              + ac * bf2f(vc[j]) + ad * bf2f(vd[j]);
    }
  }
  #pragma unroll
  for (int j = 0; j < 8; ++j){
    acc[j] += __shfl_xor(acc[j], 16, 64);
    acc[j] += __shfl_xor(acc[j], 32, 64);
  }
  dsum += __shfl_xor(dsum, 16, 64);
  dsum += __shfl_xor(dsum, 32, 64);
  if (g4 == 0){
    float dinv = 1.0f / (dsum + 1e-20f);
    ushort8_t o;
    #pragma unroll
    for (int j = 0; j < 8; ++j) o[j] = f2bf(acc[j] * dinv);
    *(ushort8_t*)(aggh + n*DIM + c16*8) = o;
  }
}

// K4: MFMA GEMM h = [embh|aggh] @ Tb^T + tb, fused LayerNorm.
// Block = 4 waves x 32 nodes (two 16-node A sets share every B frag ->
// per-wave Tb L2 traffic halved); barrier-free.
__global__ __launch_bounds__(256) void k_out(const unsigned short* __restrict__ embh,
                     const unsigned short* __restrict__ aggh,
                     const unsigned short* __restrict__ Tb,
                     const float* __restrict__ tb,
                     const float* __restrict__ gamma, const float* __restrict__ beta,
                     float* __restrict__ out){
  int t = threadIdx.x;
  int w = t >> 6;
  int lane = t & 63;
  int m16 = lane & 15;
  int q = lane >> 4;                         // 0..3
  int nodebase = blockIdx.x * 128 + w * 32;
  int nA0 = nodebase + m16;
  int nA1 = nodebase + 16 + m16;
  int nA0c = (nA0 < NN) ? nA0 : 0;           // clamp loads; stores guarded
  int nA1c = (nA1 < NN) ? nA1 : 0;
  floatx4 acc[2][8];
  #pragma unroll
  for (int st = 0; st < 2; ++st)
    #pragma unroll
    for (int ct = 0; ct < 8; ++ct) acc[st][ct] = (floatx4){0.f, 0.f, 0.f, 0.f};

  #pragma unroll
  for (int kc = 0; kc < 8; ++kc){
    int k0 = kc*32 + q*8;
    const unsigned short* ap0 = (kc < 4) ? (embh + nA0c*DIM + k0)
                                         : (aggh + nA0c*DIM + (k0 - 128));
    const unsigned short* ap1 = (kc < 4) ? (embh + nA1c*DIM + k0)
                                         : (aggh + nA1c*DIM + (k0 - 128));
    short8_t afrag0 = *(const short8_t*)ap0;           // A[m][k0..k0+7]
    short8_t afrag1 = *(const short8_t*)ap1;
    #pragma unroll
    for (int ct = 0; ct < 8; ++ct){
      short8_t bfrag = *(const short8_t*)(Tb + (ct*16 + m16)*256 + k0); // B[k][j]=T[j][k]
      acc[0][ct] = __builtin_amdgcn_mfma_f32_16x16x32_bf16(afrag0, bfrag, acc[0][ct], 0, 0, 0);
      acc[1][ct] = __builtin_amdgcn_mfma_f32_16x16x32_bf16(afrag1, bfrag, acc[1][ct], 0, 0, 0);
    }
  }

  float tbv[8], gmv[8], btv[8];
  #pragma unroll
  for (int ct = 0; ct < 8; ++ct){
    int col = ct*16 + m16;
    tbv[ct] = tb[col]; gmv[ct] = gamma[col]; btv[ct] = beta[col];
  }
  #pragma unroll
  for (int st = 0; st < 2; ++st){
    #pragma unroll
    for (int r = 0; r < 4; ++r){
      int n = nodebase + st*16 + q*4 + r;    // D row = q*4 + reg
      float h[8]; float s = 0.f, ss = 0.f;
      #pragma unroll
      for (int ct = 0; ct < 8; ++ct){
        h[ct] = acc[st][ct][r] + tbv[ct];
        s += h[ct]; ss += h[ct]*h[ct];
      }
      #pragma unroll
      for (int off = 1; off < 16; off <<= 1){
        s  += __shfl_xor(s,  off, 16);
        ss += __shfl_xor(ss, off, 16);
      }
      float mu = s * (1.f/128.f);
      float var = ss * (1.f/128.f) - mu*mu;
      float rstd = rsqrtf(var + 1e-5f);
      if (n < NN){
        #pragma unroll
        for (int ct = 0; ct < 8; ++ct){
          out[n*DIM + ct*16 + m16] = (h[ct]-mu)*rstd*gmv[ct] + btv[ct];
        }
      }
    }
  }
}

extern "C" void kernel_launch(void* const* d_in, const int* in_sizes, int n_in,
                              void* d_out, int out_size, void* d_ws, size_t ws_size,
                              hipStream_t stream){
  const float* emb          = (const float*)d_in[0];
  const int*   edges        = (const int*)d_in[1];
  const float* w_weight     = (const float*)d_in[2];
  const float* w_bias       = (const float*)d_in[3];
  const float* a_weight     = (const float*)d_in[4];
  const float* a_bias       = (const float*)d_in[5];
  const float* trans_weight = (const float*)d_in[6];
  const float* trans_bias   = (const float*)d_in[7];
  const float* ln_gamma     = (const float*)d_in[8];
  const float* ln_beta      = (const float*)d_in[9];
  float* out = (float*)d_out;

  // ws layout (float offsets), ws is 256 MiB:
  // p1[50k] p2[50k] v12c[320] | count[50k] | gcount (196 padded lines, 3136) |
  //   csr (3.2M ints) | bpool (196*4608 ints) | embh bf16[6.4M] |
  //   aggh bf16[6.4M] | Tb bf16[32768]
  float* ws      = (float*)d_ws;
  float* p1      = ws;
  float* p2      = ws + 50000;
  float* v12c    = ws + 100000;
  int*   count   = (int*)(ws + 100320);
  int*   gcount  = (int*)(ws + 150320);
  int*   csr     = (int*)(ws + 153472);
  int*   bpool   = (int*)(ws + 3353472);
  unsigned short* embh = (unsigned short*)(ws + 4256640);
  unsigned short* aggh = (unsigned short*)(ws + 7456640);
  unsigned short* Tb   = (unsigned short*)(ws + 10656640);

  const int* e_dst = edges;
  const int* e_src = edges + NE;

  k_setup<<<46, 256, 0, stream>>>(w_weight, w_bias, a_weight, a_bias, v12c,
                                  (const float4*)trans_weight, (ushort4*)Tb, gcount);
  k_A<<<NEB + (NN + 7)/8, 256, 0, stream>>>((const float4*)emb, v12c, p1, p2,
                                            embh, e_dst, e_src, gcount, bpool);
  k_B<<<NBKT, 256, 0, stream>>>(gcount, bpool, count, csr);
  k_gather<<<(NN + 3)/4, 256, 0, stream>>>(count, csr, p1, p2, embh, aggh);
  k_out<<<(NN + 127)/128, 256, 0, stream>>>(embh, aggh, Tb, trans_bias,
                                            ln_gamma, ln_beta, out);
}

// Round 7
// 171.301 us; speedup vs baseline: 1.3134x; 1.0289x over previous
//
#include <hip/hip_runtime.h>
#include <hip/hip_bf16.h>

#define NN 50000
#define NE 800000
#define DIM 128
#define NBKT 196        // ceil(50000/256); bucket = dst>>8 (256 nodes/bucket)
#define BKTCAP 4608     // slots/bucket (mean 4096, +8 sigma; P(ovf)~1e-13)
#define CAP 64          // padded-CSR slots per node (lambda=16; P(ovf)~1e-15)
#define EPB 4096        // edges per phase-A block
#define NEB 196         // ceil(NE/EPB) edge blocks

typedef __attribute__((ext_vector_type(8))) short short8_t;           // 8 bf16 for MFMA
typedef __attribute__((ext_vector_type(8))) unsigned short ushort8_t; // 8 bf16 raw
typedef __attribute__((ext_vector_type(4))) float floatx4;

static __device__ inline unsigned short f2bf(float x){        // RNE float->bf16
  unsigned int u = __float_as_uint(x);
  unsigned int r = (u + 0x7FFF + ((u >> 16) & 1)) >> 16;
  return (unsigned short)r;
}
static __device__ inline float bf2f(unsigned short u){
  return __uint_as_float(((unsigned int)u) << 16);
}

// K0: heterogeneous setup. Block 0: fold W into attention vectors
// (v1 = a1^T W, v2 = a2^T W, c1 = b.a1 + a_bias, c2 = b.a2).
// Blocks 1..32: T f32 -> bf16. Blocks 33..45: zero padded gcount (3136 ints).
__global__ __launch_bounds__(256) void k_setup(const float* __restrict__ W,
                       const float* __restrict__ wb,
                       const float* __restrict__ aw, const float* __restrict__ ab,
                       float* __restrict__ v12c,
                       const float4* __restrict__ T4, ushort4* __restrict__ Tb4,
                       int* __restrict__ gcount){
  int b = blockIdx.x;
  int t = threadIdx.x;
  if (b == 0){
    __shared__ float r1[DIM], r2[DIM];
    if (t < DIM){
      float s1 = 0.f, s2 = 0.f;
      for (int j = 0; j < DIM; ++j){
        float w = W[j*DIM + t];
        s1 += aw[j] * w;
        s2 += aw[DIM + j] * w;
      }
      v12c[t] = s1;
      v12c[DIM + t] = s2;
      float bb = wb[t];
      r1[t] = bb * aw[t];
      r2[t] = bb * aw[DIM + t];
    }
    __syncthreads();
    if (t == 0){
      float a1s = 0.f, a2s = 0.f;
      for (int j = 0; j < DIM; ++j){ a1s += r1[j]; a2s += r2[j]; }
      v12c[2*DIM]   = a1s + ab[0];
      v12c[2*DIM+1] = a2s;
    }
  } else if (b <= 32){
    int i = (b-1)*256 + t;              // 8192 float4s of T
    float4 v = T4[i];
    Tb4[i] = make_ushort4(f2bf(v.x), f2bf(v.y), f2bf(v.z), f2bf(v.w));
  } else {
    int i = (b-33)*256 + t;             // NBKT*16 = 3136 padded counters
    if (i < NBKT*16) gcount[i] = 0;
  }
}

// K1 (phase A, fused): blocks 0..NEB-1 bucket the edges; blocks NEB.. do
// p1/p2 + bf16 emb copy. Edge path: LDS rank within (block,bucket), ONE
// global atomic per (block,bucket) -> 38K global atomics total.
// EPB=4096: ~21-int contiguous chunks per (block,bucket) in bpool.
// Packed edge = (local_d<<16)|src (local_d<256, src<65536).
__global__ __launch_bounds__(256) void k_A(const float4* __restrict__ emb4,
                      const float* __restrict__ v12c,
                      float* __restrict__ p1, float* __restrict__ p2,
                      unsigned short* __restrict__ embh,
                      const int* __restrict__ dst, const int* __restrict__ srcp,
                      int* __restrict__ gcount, int* __restrict__ bpool){
  if (blockIdx.x < NEB){
    __shared__ int bcnt[NBKT], bbase[NBKT];
    int t = threadIdx.x;
    if (t < NBKT) bcnt[t] = 0;
    __syncthreads();
    int rnk[16], bkt[16], pk[16];
    #pragma unroll
    for (int j = 0; j < 16; ++j){
      int e = blockIdx.x * EPB + j*256 + t;
      bkt[j] = -1;
      if (e < NE){
        int d = dst[e], s = srcp[e];
        bkt[j] = d >> 8;
        pk[j] = ((d & 255) << 16) | s;
        rnk[j] = atomicAdd(&bcnt[bkt[j]], 1);     // LDS atomic
      }
    }
    __syncthreads();
    if (t < NBKT) bbase[t] = atomicAdd(&gcount[t*16], bcnt[t]);  // global, padded line
    __syncthreads();
    #pragma unroll
    for (int j = 0; j < 16; ++j){
      if (bkt[j] >= 0){
        int pos = bbase[bkt[j]] + rnk[j];
        if (pos < BKTCAP) bpool[bkt[j]*BKTCAP + pos] = pk[j];
      }
    }
    return;
  }
  // node work
  int g = threadIdx.x & 31;
  int i = (blockIdx.x - NEB) * 8 + (threadIdx.x >> 5);
  if (i >= NN) return;
  float4 e = emb4[i*32 + g];
  *(ushort4*)(embh + i*DIM + g*4) =
      make_ushort4(f2bf(e.x), f2bf(e.y), f2bf(e.z), f2bf(e.w));
  float4 a = ((const float4*)v12c)[g];
  float4 b = ((const float4*)v12c)[32 + g];
  float s1 = e.x*a.x + e.y*a.y + e.z*a.z + e.w*a.w;
  float s2 = e.x*b.x + e.y*b.y + e.z*b.z + e.w*b.w;
  #pragma unroll
  for (int off = 16; off; off >>= 1){
    s1 += __shfl_down(s1, off, 32);
    s2 += __shfl_down(s2, off, 32);
  }
  if (g == 0){
    p1[i] = s1 + v12c[256];
    p2[i] = s2 + v12c[257];
  }
}

// K2 (phase B): one 1024-thread block per bucket (serial depth 18 -> 5,
// fills 16 waves on each of its 196 CUs). Coalesced read of the bucket's
// packed edges, exact per-node rank via 256 LDS counters (ZERO global
// atomics), write padded per-node CSR (64KB window) + dense count[n].
__global__ __launch_bounds__(1024) void k_B(const int* __restrict__ gcount,
                      const int* __restrict__ bpool,
                      int* __restrict__ count, int* __restrict__ csr){
  __shared__ int cnt[256];
  int b = blockIdx.x, t = threadIdx.x;
  if (t < 256) cnt[t] = 0;
  __syncthreads();
  int m = gcount[b*16]; if (m > BKTCAP) m = BKTCAP;
  int base = b * BKTCAP;
  int rnk[5], pkv[5];
  #pragma unroll
  for (int it = 0; it < 5; ++it){     // 5*1024 = 5120 >= BKTCAP
    int e = it*1024 + t;
    pkv[it] = -1;
    if (e < m){
      int pk = bpool[base + e];
      pkv[it] = pk;
      rnk[it] = atomicAdd(&cnt[(pk >> 16) & 255], 1);   // LDS atomic
    }
  }
  __syncthreads();
  if (t < 256){
    int n = b*256 + t;
    if (n < NN){ int c = cnt[t]; count[n] = c < CAP ? c : CAP; }
  }
  #pragma unroll
  for (int it = 0; it < 5; ++it){
    if (pkv[it] >= 0 && rnk[it] < CAP){
      int d = b*256 + ((pkv[it] >> 16) & 255);
      csr[(d << 6) + rnk[it]] = pkv[it] & 0xFFFF;
    }
  }
}

// K3: one 64-lane wave per destination node (16 lanes x 16B = one 256B bf16
// row per edge slot). BRANCH-FREE 4-deep pipeline: edges e,e+4,e+8,e+12 per
// iteration; inactive slots clamp to source 0 (always-valid memory) with
// weight forced to 0, so all 4 csr reads + 4 p2 reads + 4 row loads issue
// unconditionally with no exec-mask control flow.
__global__ __launch_bounds__(256) void k_gather(const int* __restrict__ count,
                       const int* __restrict__ csr,
                       const float* __restrict__ p1, const float* __restrict__ p2,
                       const unsigned short* __restrict__ embh,
                       unsigned short* __restrict__ aggh){
  int lane = threadIdx.x & 63;
  int c16 = lane & 15;                 // column slot (8 bf16 each)
  int g4 = lane >> 4;                  // edge slot 0..3
  int n = blockIdx.x * 4 + (threadIdx.x >> 6);
  if (n >= NN) return;
  int cnt = count[n];                  // pre-capped at 64
  int s0 = n << 6;
  float p1n = p1[n];
  float acc[8] = {0.f,0.f,0.f,0.f,0.f,0.f,0.f,0.f};
  float dsum = 0.f;
  for (int e = g4; e < cnt; e += 16){
    int e1 = e + 4, e2 = e + 8, e3 = e + 12;
    int sa = csr[s0 + e];
    int sb = csr[e1 < cnt ? s0 + e1 : s0];
    int sc = csr[e2 < cnt ? s0 + e2 : s0];
    int sd = csr[e3 < cnt ? s0 + e3 : s0];
    float fa = p1n + p2[sa];
    float fb = p1n + p2[sb];
    float fc = p1n + p2[sc];
    float fd = p1n + p2[sd];
    fa = fa > 0.f ? fa : 0.2f * fa;
    fb = fb > 0.f ? fb : 0.2f * fb;
    fc = fc > 0.f ? fc : 0.2f * fc;
    fd = fd > 0.f ? fd : 0.2f * fd;
    float aa = __expf(fa);
    float ab_ = (e1 < cnt) ? __expf(fb) : 0.f;
    float ac = (e2 < cnt) ? __expf(fc) : 0.f;
    float ad = (e3 < cnt) ? __expf(fd) : 0.f;
    dsum += aa + ab_ + ac + ad;
    const ushort8_t va = *(const ushort8_t*)(embh + sa*DIM + c16*8);  // 256B/group
    const ushort8_t vb = *(const ushort8_t*)(embh + sb*DIM + c16*8);
    const ushort8_t vc = *(const ushort8_t*)(embh + sc*DIM + c16*8);
    const ushort8_t vd = *(const ushort8_t*)(embh + sd*DIM + c16*8);
    #pragma unroll
    for (int j = 0; j < 8; ++j){
      acc[j] += aa * bf2f(va[j]) + ab_ * bf2f(vb[j])
              + ac * bf2f(vc[j]) + ad * bf2f(vd[j]);
    }
  }
  #pragma unroll
  for (int j = 0; j < 8; ++j){
    acc[j] += __shfl_xor(acc[j], 16, 64);
    acc[j] += __shfl_xor(acc[j], 32, 64);
  }
  dsum += __shfl_xor(dsum, 16, 64);
  dsum += __shfl_xor(dsum, 32, 64);
  if (g4 == 0){
    float dinv = 1.0f / (dsum + 1e-20f);
    ushort8_t o;
    #pragma unroll
    for (int j = 0; j < 8; ++j) o[j] = f2bf(acc[j] * dinv);
    *(ushort8_t*)(aggh + n*DIM + c16*8) = o;
  }
}

// K4: MFMA GEMM h = [embh|aggh] @ Tb^T + tb, fused LayerNorm.
// Block = 4 waves x 32 nodes (two 16-node A sets share every B frag ->
// per-wave Tb L2 traffic halved); barrier-free.
__global__ __launch_bounds__(256) void k_out(const unsigned short* __restrict__ embh,
                     const unsigned short* __restrict__ aggh,
                     const unsigned short* __restrict__ Tb,
                     const float* __restrict__ tb,
                     const float* __restrict__ gamma, const float* __restrict__ beta,
                     float* __restrict__ out){
  int t = threadIdx.x;
  int w = t >> 6;
  int lane = t & 63;
  int m16 = lane & 15;
  int q = lane >> 4;                         // 0..3
  int nodebase = blockIdx.x * 128 + w * 32;
  int nA0 = nodebase + m16;
  int nA1 = nodebase + 16 + m16;
  int nA0c = (nA0 < NN) ? nA0 : 0;           // clamp loads; stores guarded
  int nA1c = (nA1 < NN) ? nA1 : 0;
  floatx4 acc[2][8];
  #pragma unroll
  for (int st = 0; st < 2; ++st)
    #pragma unroll
    for (int ct = 0; ct < 8; ++ct) acc[st][ct] = (floatx4){0.f, 0.f, 0.f, 0.f};

  #pragma unroll
  for (int kc = 0; kc < 8; ++kc){
    int k0 = kc*32 + q*8;
    const unsigned short* ap0 = (kc < 4) ? (embh + nA0c*DIM + k0)
                                         : (aggh + nA0c*DIM + (k0 - 128));
    const unsigned short* ap1 = (kc < 4) ? (embh + nA1c*DIM + k0)
                                         : (aggh + nA1c*DIM + (k0 - 128));
    short8_t afrag0 = *(const short8_t*)ap0;           // A[m][k0..k0+7]
    short8_t afrag1 = *(const short8_t*)ap1;
    #pragma unroll
    for (int ct = 0; ct < 8; ++ct){
      short8_t bfrag = *(const short8_t*)(Tb + (ct*16 + m16)*256 + k0); // B[k][j]=T[j][k]
      acc[0][ct] = __builtin_amdgcn_mfma_f32_16x16x32_bf16(afrag0, bfrag, acc[0][ct], 0, 0, 0);
      acc[1][ct] = __builtin_amdgcn_mfma_f32_16x16x32_bf16(afrag1, bfrag, acc[1][ct], 0, 0, 0);
    }
  }

  float tbv[8], gmv[8], btv[8];
  #pragma unroll
  for (int ct = 0; ct < 8; ++ct){
    int col = ct*16 + m16;
    tbv[ct] = tb[col]; gmv[ct] = gamma[col]; btv[ct] = beta[col];
  }
  #pragma unroll
  for (int st = 0; st < 2; ++st){
    #pragma unroll
    for (int r = 0; r < 4; ++r){
      int n = nodebase + st*16 + q*4 + r;    // D row = q*4 + reg
      float h[8]; float s = 0.f, ss = 0.f;
      #pragma unroll
      for (int ct = 0; ct < 8; ++ct){
        h[ct] = acc[st][ct][r] + tbv[ct];
        s += h[ct]; ss += h[ct]*h[ct];
      }
      #pragma unroll
      for (int off = 1; off < 16; off <<= 1){
        s  += __shfl_xor(s,  off, 16);
        ss += __shfl_xor(ss, off, 16);
      }
      float mu = s * (1.f/128.f);
      float var = ss * (1.f/128.f) - mu*mu;
      float rstd = rsqrtf(var + 1e-5f);
      if (n < NN){
        #pragma unroll
        for (int ct = 0; ct < 8; ++ct){
          out[n*DIM + ct*16 + m16] = (h[ct]-mu)*rstd*gmv[ct] + btv[ct];
        }
      }
    }
  }
}

extern "C" void kernel_launch(void* const* d_in, const int* in_sizes, int n_in,
                              void* d_out, int out_size, void* d_ws, size_t ws_size,
                              hipStream_t stream){
  const float* emb          = (const float*)d_in[0];
  const int*   edges        = (const int*)d_in[1];
  const float* w_weight     = (const float*)d_in[2];
  const float* w_bias       = (const float*)d_in[3];
  const float* a_weight     = (const float*)d_in[4];
  const float* a_bias       = (const float*)d_in[5];
  const float* trans_weight = (const float*)d_in[6];
  const float* trans_bias   = (const float*)d_in[7];
  const float* ln_gamma     = (const float*)d_in[8];
  const float* ln_beta      = (const float*)d_in[9];
  float* out = (float*)d_out;

  // ws layout (float offsets), ws is 256 MiB:
  // p1[50k] p2[50k] v12c[320] | count[50k] | gcount (196 padded lines, 3136) |
  //   csr (3.2M ints) | bpool (196*4608 ints) | embh bf16[6.4M] |
  //   aggh bf16[6.4M] | Tb bf16[32768]
  float* ws      = (float*)d_ws;
  float* p1      = ws;
  float* p2      = ws + 50000;
  float* v12c    = ws + 100000;
  int*   count   = (int*)(ws + 100320);
  int*   gcount  = (int*)(ws + 150320);
  int*   csr     = (int*)(ws + 153472);
  int*   bpool   = (int*)(ws + 3353472);
  unsigned short* embh = (unsigned short*)(ws + 4256640);
  unsigned short* aggh = (unsigned short*)(ws + 7456640);
  unsigned short* Tb   = (unsigned short*)(ws + 10656640);

  const int* e_dst = edges;
  const int* e_src = edges + NE;

  k_setup<<<46, 256, 0, stream>>>(w_weight, w_bias, a_weight, a_bias, v12c,
                                  (const float4*)trans_weight, (ushort4*)Tb, gcount);
  k_A<<<NEB + (NN + 7)/8, 256, 0, stream>>>((const float4*)emb, v12c, p1, p2,
                                            embh, e_dst, e_src, gcount, bpool);
  k_B<<<NBKT, 1024, 0, stream>>>(gcount, bpool, count, csr);
  k_gather<<<(NN + 3)/4, 256, 0, stream>>>(count, csr, p1, p2, embh, aggh);
  k_out<<<(NN + 127)/128, 256, 0, stream>>>(embh, aggh, Tb, trans_bias,
                                            ln_gamma, ln_beta, out);
}